// Round 4
// baseline (416.716 us; speedup 1.0000x reference)
//
#include <hip/hip_runtime.h>
#include <hip/hip_bf16.h>

// BayesianKAN_ECG: x[65536,1000] f32 -> pool10 -> norm(ddof=1) -> KAN1(RBF16,
// 100->64) -> tanh -> norm -> KAN2(RBF16, 64->5) -> fp32 out [65536,5].
//
// R9: split the HBM stream from the compute. R8 (153us) was burst+idle:
// all resident waves pool simultaneously (HBM burst, everyone parked on
// vmcnt), then compute with HBM idle, x2 generations. Now:
//  - pool_norm kernel: pure streaming pool+norm (R8's register code), writes
//    normalized PRE-SCALED xn[65536][100] f32 (26 MB) to workspace. Massive
//    MLP, oversubscribed grid -> near-peak BW, ~35us.
//  - kan_main: R8 verbatim, but pool replaced by a 6.4KB LDS stage of the
//    block's xn tile (L2/L3-resident). No HBM dependence at all -> pure
//    compute/L2, latency well-hidden at 24 waves/CU.
//  - weights fragment-major (R8), 1-deep prefetch, exp2 pre-scaled basis,
//    in-register norm-h, K-split KAN1/KAN2 (R7/R8 skeleton).

#define SEQ    1000
#define INDIM  100
#define HID    64
#define OUTD   5
#define ROWS   16
#define NTHR   128

typedef __bf16 v8bf __attribute__((ext_vector_type(8)));
typedef float  v4f  __attribute__((ext_vector_type(4)));

#define XSTR 104   // xn stride (f32), 16B-multiple for float4 LDS stage
#define HSTR 65    // hb stride (f32)
#define RSTR 68    // red stride (f32)
#define R2STR 20   // red2 stride (f32)

#if __has_builtin(__builtin_amdgcn_exp2f)
#define EXP2(x) __builtin_amdgcn_exp2f(x)
#else
#define EXP2(x) exp2f(x)
#endif
#if __has_builtin(__builtin_amdgcn_rcpf)
#define RCP(x) __builtin_amdgcn_rcpf(x)
#else
#define RCP(x) (1.f / (x))
#endif
#if __has_builtin(__builtin_amdgcn_sqrtf)
#define SQRT(x) __builtin_amdgcn_sqrtf(x)
#else
#define SQRT(x) sqrtf(x)
#endif

// ---- pre-kernel: permute weights to fragment-major bf16 (see R8).
__global__ __launch_bounds__(256) void cvt_w(
    const float* __restrict__ c1, const float* __restrict__ c2,
    __bf16* __restrict__ c1p, __bf16* __restrict__ c2p)
{
  int t = blockIdx.x * 256 + threadIdx.x;
  if (t < 12800) {
    int lane = t & 63, frag = t >> 6;
    int cb = frag & 3, ks = frag >> 2;
    int l15 = lane & 15, q = lane >> 4;
    const float4* s = (const float4*)(c1 + (size_t)(cb * 16 + l15) * 1600 + ks * 32 + q * 8);
    float4 v0 = s[0], v1 = s[1];
    __bf16* d = c1p + (size_t)t * 8;
    d[0]=(__bf16)v0.x; d[1]=(__bf16)v0.y; d[2]=(__bf16)v0.z; d[3]=(__bf16)v0.w;
    d[4]=(__bf16)v1.x; d[5]=(__bf16)v1.y; d[6]=(__bf16)v1.z; d[7]=(__bf16)v1.w;
  }
  if (t < 2048) {
    int lane = t & 63, t8 = t >> 6;
    int row = lane & 15, q = lane >> 4;
    __bf16* d = c2p + (size_t)t * 8;
    if (row < OUTD) {
      const float4* s = (const float4*)(c2 + (size_t)row * 1024 + t8 * 32 + q * 8);
      float4 v0 = s[0], v1 = s[1];
      d[0]=(__bf16)v0.x; d[1]=(__bf16)v0.y; d[2]=(__bf16)v0.z; d[3]=(__bf16)v0.w;
      d[4]=(__bf16)v1.x; d[5]=(__bf16)v1.y; d[6]=(__bf16)v1.z; d[7]=(__bf16)v1.w;
    } else {
      #pragma unroll
      for (int j = 0; j < 8; ++j) d[j] = (__bf16)0.f;
    }
  }
}

// ---- pool + norm streaming kernel: 32 rows/block of 256 thr.
// Lane map pr = tid>>3 (line-dense reads), slot = tid&7; raw sums (no /10,
// eps 1e-6 -> 1e-5 exactly); output PRE-SCALED by Sn2 for exp2 basis.
__global__ __launch_bounds__(256, 4) void pool_norm(
    const float* __restrict__ x, float* __restrict__ xnb)
{
  const int tid  = threadIdx.x;
  const int row0 = blockIdx.x * 32;
  const int pr   = tid >> 3;           // 0..31
  const int slot = tid & 7;
  const float Sn2 = 1.41553628f;       // sqrt(0.5/0.36 * log2 e)

  float pva[14];
  float s = 0.f, s2 = 0.f;
  {
    const float* xg = x + (size_t)(row0 + pr) * SEQ;
    #pragma unroll
    for (int it = 0; it < 7; ++it) {
      int p = slot + (it << 3);
      float u0 = 0.f, u1 = 0.f;
      if (p < 50) {
        const float4* xp = (const float4*)(xg + p * 20);
        float4 a0 = xp[0], a1 = xp[1], a2 = xp[2], a3 = xp[3], a4 = xp[4];
        u0 = a0.x+a0.y+a0.z+a0.w + a1.x+a1.y+a1.z+a1.w + a2.x+a2.y;
        u1 = a2.z+a2.w + a3.x+a3.y+a3.z+a3.w + a4.x+a4.y+a4.z+a4.w;
        s += u0 + u1; s2 += u0*u0 + u1*u1;
      }
      pva[2*it] = u0; pva[2*it+1] = u1;
    }
  }
  #pragma unroll
  for (int m = 1; m <= 4; m <<= 1) {
    s += __shfl_xor(s, m, 64); s2 += __shfl_xor(s2, m, 64);
  }
  float mu  = s * 0.01f;
  float var = (s2 - 100.f * mu * mu) * (1.f / 99.f);
  float rs  = Sn2 * RCP(SQRT(fmaxf(var, 0.f)) + 1e-5f);
  float* xo = xnb + (size_t)(row0 + pr) * INDIM;
  #pragma unroll
  for (int it = 0; it < 7; ++it) {
    int p = slot + (it << 3);
    if (p < 50) {
      float2 v2;
      v2.x = (pva[2*it]     - mu) * rs;
      v2.y = (pva[2*it + 1] - mu) * rs;
      *(float2*)(xo + 2 * p) = v2;
    }
  }
}

#define MFMA __builtin_amdgcn_mfma_f32_16x16x32_bf16

__global__ __launch_bounds__(NTHR, 6) void kan_main(
    const float* __restrict__ xnb, const __bf16* __restrict__ c1p,
    const __bf16* __restrict__ c2p, const float* __restrict__ cen,
    float* __restrict__ out)
{
  // LDS (floats), phases alias:
  //  P1: xn[16][104] @0 (1664)
  //  P2: red[16][68] @0 (1088, xn dead), hb[16][65] @1664 (1040)
  //  P3: red2[16][20] @0 (320)
  __shared__ __align__(16) float sm[2704];   // 10.8 KB
  float* xn   = sm;
  float* red  = sm;
  float* hb   = sm + 1664;
  float* red2 = sm;

  const int tid  = threadIdx.x;
  const int w    = tid >> 6, lane = tid & 63;
  const int row0 = blockIdx.x * ROWS;
  const int l15 = lane & 15, q = lane >> 4, iq = q >> 1;

  const float Sn2 = 1.41553628f;
  const float TL2 = 2.88539008f;             // 2*log2(e) for tanh
  float cs[8];
  {
    const int n0 = (q & 1) * 8;
    #pragma unroll
    for (int j = 0; j < 8; ++j) cs[j] = cen[n0 + j] * Sn2;
  }

  // ---- stage normalized tile from global (L2/L3-resident, 26MB buffer) ----
  #pragma unroll
  for (int it = 0; it < 4; ++it) {
    int idx = tid + it * NTHR;                 // < 400 quads (16 rows x 25)
    if (idx < 400) {
      int r = idx / 25, q4 = idx - r * 25;
      float4 v = *(const float4*)(xnb + (size_t)(row0 + r) * INDIM + q4 * 4);
      *(float4*)(xn + r * XSTR + q4 * 4) = v;
    }
  }
  __syncthreads();

  // ---- KAN1 (K-split): wave w does global ksteps 25w..25w+24 (K=800).
  //      B-fragments contiguous (fragment-major); 1-ahead prefetch.
  const float* xr = xn + l15 * XSTR;
  const __bf16* bp = c1p + (size_t)(51200 * w) + lane * 8;
  v4f acc[4];
  acc[0] = (v4f){0.f,0.f,0.f,0.f}; acc[1] = acc[0]; acc[2] = acc[0]; acc[3] = acc[0];

  v8bf bA0 = *(const v8bf*)(bp +    0);
  v8bf bA1 = *(const v8bf*)(bp +  512);
  v8bf bA2 = *(const v8bf*)(bp + 1024);
  v8bf bA3 = *(const v8bf*)(bp + 1536);
  bp += 2048;

  #pragma unroll
  for (int c5 = 0; c5 < 5; ++c5) {
    const int c = w * 5 + c5;
    float xv[5];
    #pragma unroll
    for (int k = 0; k < 5; ++k) xv[k] = xr[c * 10 + 2 * k + iq];
    #pragma unroll
    for (int ks = 0; ks < 5; ++ks) {
      v8bf nb0, nb1, nb2, nb3;
      if (c5 * 5 + ks < 24) {
        nb0 = *(const v8bf*)(bp +    0);
        nb1 = *(const v8bf*)(bp +  512);
        nb2 = *(const v8bf*)(bp + 1024);
        nb3 = *(const v8bf*)(bp + 1536);
      }
      bp += 2048;
      v8bf a;
      {
        float xvk = xv[ks];
        #pragma unroll
        for (int j = 0; j < 8; ++j) {
          float d = xvk - cs[j];
          a[j] = (__bf16)EXP2(-(d * d));
        }
      }
      acc[0] = MFMA(a, bA0, acc[0], 0, 0, 0);
      acc[1] = MFMA(a, bA1, acc[1], 0, 0, 0);
      acc[2] = MFMA(a, bA2, acc[2], 0, 0, 0);
      acc[3] = MFMA(a, bA3, acc[3], 0, 0, 0);
      if (c5 * 5 + ks < 24) { bA0 = nb0; bA1 = nb1; bA2 = nb2; bA3 = nb3; }
    }
  }
  __syncthreads();

  // ---- combine K-halves: wave w gives away rg = {2(1-w),..}, owns {2w,..};
  //      tanh + in-register norm-h on own rows ----
  #pragma unroll
  for (int rgo = 0; rgo < 2; ++rgo) {
    int rg = 2 * (1 - w) + rgo;
    #pragma unroll
    for (int cb = 0; cb < 4; ++cb)
      red[(q * 4 + rg) * RSTR + cb * 16 + l15] = acc[cb][rg];
  }
  __syncthreads();
  #pragma unroll
  for (int rgo = 0; rgo < 2; ++rgo) {
    int rg = 2 * w + rgo;
    float h[4], ss = 0.f, ss2 = 0.f;
    #pragma unroll
    for (int cb = 0; cb < 4; ++cb) {
      float t = acc[cb][rg] + red[(q * 4 + rg) * RSTR + cb * 16 + l15];
      float e = EXP2(t * TL2);                       // e^{2t}
      float hv = 1.f - 2.f * RCP(e + 1.f);           // tanh
      h[cb] = hv; ss += hv; ss2 += hv * hv;
    }
    #pragma unroll
    for (int m = 1; m <= 8; m <<= 1) {
      ss += __shfl_xor(ss, m, 64); ss2 += __shfl_xor(ss2, m, 64);
    }
    float muh  = ss * (1.f / 64.f);
    float varh = (ss2 - 64.f * muh * muh) * (1.f / 63.f);
    float rsh  = Sn2 * RCP(SQRT(fmaxf(varh, 0.f)) + 1e-6f);
    #pragma unroll
    for (int cb = 0; cb < 4; ++cb)
      hb[(q * 4 + rg) * HSTR + cb * 16 + l15] = (h[cb] - muh) * rsh;  // pre-scaled
  }
  __syncthreads();

  // ---- KAN2 (K-split): wave w does t8 = 16w..16w+15 (K=512) ----
  const float* hr = hb + l15 * HSTR;
  float hv16[16];
  #pragma unroll
  for (int t = 0; t < 16; ++t) hv16[t] = hr[2 * (16 * w + t) + iq];
  const __bf16* bp2 = c2p + (size_t)(16 * w) * 512 + lane * 8;
  v8bf vb = *(const v8bf*)(bp2);
  v4f o4 = (v4f){0.f, 0.f, 0.f, 0.f};
  #pragma unroll
  for (int t = 0; t < 16; ++t) {
    v8bf nvb;
    if (t < 15) nvb = *(const v8bf*)(bp2 + (t + 1) * 512);
    v8bf a;
    {
      float hvv = hv16[t];
      #pragma unroll
      for (int j = 0; j < 8; ++j) {
        float d = hvv - cs[j];
        a[j] = (__bf16)EXP2(-(d * d));
      }
    }
    o4 = MFMA(a, vb, o4, 0, 0, 0);
    if (t < 15) vb = nvb;
  }
  if (w == 0) {
    #pragma unroll
    for (int rg = 0; rg < 4; ++rg)
      red2[(q * 4 + rg) * R2STR + l15] = o4[rg];
  }
  __syncthreads();
  if (w == 1 && l15 < OUTD) {
    #pragma unroll
    for (int rg = 0; rg < 4; ++rg) {
      int r = q * 4 + rg;
      out[(size_t)(row0 + r) * OUTD + l15] = o4[rg] + red2[r * R2STR + l15];
    }
  }
}

extern "C" void kernel_launch(void* const* d_in, const int* in_sizes, int n_in,
                              void* d_out, int out_size, void* d_ws, size_t ws_size,
                              hipStream_t stream) {
  const float* x   = (const float*)d_in[0];
  const float* c1  = (const float*)d_in[1];
  const float* c2  = (const float*)d_in[2];
  const float* cen = (const float*)d_in[3];
  float* out = (float*)d_out;

  __bf16* c1p = (__bf16*)d_ws;                         // 204,800 B
  __bf16* c2p = (__bf16*)((char*)d_ws + 204800);       //  32,768 B
  float*  xnb = (float*)((char*)d_ws + 237568);        // 26,214,400 B

  hipLaunchKernelGGL(cvt_w, dim3(50), dim3(256), 0, stream, c1, c2, c1p, c2p);
  hipLaunchKernelGGL(pool_norm, dim3(65536 / 32), dim3(256), 0, stream, x, xnb);
  hipLaunchKernelGGL(kan_main, dim3(65536 / ROWS), dim3(NTHR), 0, stream,
                     xnb, c1p, c2p, cen, out);
}